// Round 1
// baseline (1053.845 us; speedup 1.0000x reference)
//
#include <hip/hip_runtime.h>
#include <cstdint>

#define WSTRIDE 385  // 384 weight cols + 1 pad (bank-conflict-free LDS)

__device__ __forceinline__ float sigmoidf_(float x) {
  return 1.0f / (1.0f + __expf(-x));
}
__device__ __forceinline__ float tanhf_(float x) {
  return 2.0f / (1.0f + __expf(-2.0f * x)) - 1.0f;
}

// h[i][j] = emb[x[i]][j]
__global__ __launch_bounds__(256) void k_embed(const int* __restrict__ x,
                                               const float* __restrict__ emb,
                                               float* __restrict__ h, int N) {
  int idx = blockIdx.x * 256 + threadIdx.x;
  if (idx >= N * 64) return;
  int i = idx >> 6, j = idx & 63;
  h[idx] = emb[x[i] * 64 + j];
}

__global__ __launch_bounds__(256) void k_count(const int* __restrict__ dst,
                                               int* __restrict__ cnt, int E) {
  int e = blockIdx.x * 256 + threadIdx.x;
  if (e < E) atomicAdd(&cnt[dst[e]], 1);
}

__global__ __launch_bounds__(256) void k_scan1(const int* __restrict__ cnt,
                                               int* __restrict__ part, int N) {
  __shared__ int s[256];
  int i = blockIdx.x * 256 + threadIdx.x;
  s[threadIdx.x] = (i < N) ? cnt[i] : 0;
  __syncthreads();
  for (int off = 128; off > 0; off >>= 1) {
    if (threadIdx.x < off) s[threadIdx.x] += s[threadIdx.x + off];
    __syncthreads();
  }
  if (threadIdx.x == 0) part[blockIdx.x] = s[0];
}

__global__ __launch_bounds__(512) void k_scan2(const int* __restrict__ part,
                                               int* __restrict__ coff, int nC) {
  __shared__ int s[512];
  int t = threadIdx.x;
  int v = (t < nC) ? part[t] : 0;
  s[t] = v;
  __syncthreads();
  for (int off = 1; off < 512; off <<= 1) {
    int xx = (t >= off) ? s[t - off] : 0;
    __syncthreads();
    s[t] += xx;
    __syncthreads();
  }
  if (t < nC) coff[t] = s[t] - v;  // exclusive prefix
}

__global__ __launch_bounds__(256) void k_scan3(const int* __restrict__ cnt,
                                               const int* __restrict__ coff,
                                               int* __restrict__ rowp, int N, int E) {
  __shared__ int s[256];
  int t = threadIdx.x;
  int i = blockIdx.x * 256 + t;
  int v = (i < N) ? cnt[i] : 0;
  s[t] = v;
  __syncthreads();
  for (int off = 1; off < 256; off <<= 1) {
    int xx = (t >= off) ? s[t - off] : 0;
    __syncthreads();
    s[t] += xx;
    __syncthreads();
  }
  if (i < N) rowp[i] = coff[blockIdx.x] + s[t] - v;
  if (blockIdx.x == 0 && t == 0) rowp[N] = E;
}

__global__ __launch_bounds__(256) void k_fill(const int* __restrict__ src,
                                              const int* __restrict__ dst,
                                              const int* __restrict__ rowp,
                                              int* __restrict__ cur,
                                              int* __restrict__ ssrc, int E) {
  int e = blockIdx.x * 256 + threadIdx.x;
  if (e >= E) return;
  int d = dst[e];
  int pos = rowp[d] + atomicAdd(&cur[d], 1);
  ssrc[pos] = src[e];
}

// Wp[row][t] = sum_k wih[row][k] * ggc[t][k]   (192x64 out, row-major)
__global__ __launch_bounds__(256) void k_wcomb(const float* __restrict__ wih,
                                               const float* __restrict__ ggc,
                                               float* __restrict__ Wp) {
  int o = blockIdx.x * 256 + threadIdx.x;
  if (o >= 192 * 64) return;
  int row = o >> 6, t = o & 63;
  const float* a = wih + row * 64;
  const float* b = ggc + t * 64;
  float s = 0.0f;
#pragma unroll
  for (int k = 0; k < 64; ++k) s += a[k] * b[k];
  Wp[o] = s;
}

// aggH[n][j] = sum over incoming edges of h[src][j]  (CSR gather)
__global__ __launch_bounds__(256) void k_agg(const float* __restrict__ h,
                                             const int* __restrict__ rowp,
                                             const int* __restrict__ ssrc,
                                             float* __restrict__ aggH, int N) {
  int lane = threadIdx.x & 63;
  int n = blockIdx.x * 4 + (threadIdx.x >> 6);
  if (n >= N) return;
  int beg = rowp[n], end = rowp[n + 1];
  float acc = 0.0f;
  for (int e = beg; e < end; ++e) {
    int s = ssrc[e];
    acc += h[(size_t)s * 64 + lane];
  }
  aggH[(size_t)n * 64 + lane] = acc;
}

// Fused GRU: gi = aggH @ Wp^T + bih ; gh = h @ whh^T + bhh ; gates ; relu ; in-place h
__global__ __launch_bounds__(256) void k_gru(float* __restrict__ h,
                                             const float* __restrict__ aggH,
                                             const float* __restrict__ Wp,
                                             const float* __restrict__ whh,
                                             const float* __restrict__ bih,
                                             const float* __restrict__ bhh, int N) {
  extern __shared__ float Wc[];  // [64][WSTRIDE]: cols 0..191 = Wp rows, 192..383 = whh rows
  for (int idx = threadIdx.x; idx < 192 * 64; idx += 256) {
    int row = idx >> 6, k = idx & 63;
    Wc[k * WSTRIDE + row] = Wp[idx];
    Wc[k * WSTRIDE + 192 + row] = whh[idx];
  }
  __syncthreads();
  const int lane = threadIdx.x & 63;
  int gw = __builtin_amdgcn_readfirstlane((int)(blockIdx.x * 4 + (threadIdx.x >> 6)));
  const int nW = gridDim.x * 4;
  const int Q = (N + 3) >> 2;
  const float b_ir = bih[lane], b_iz = bih[64 + lane], b_in = bih[128 + lane];
  const float b_hr = bhh[lane], b_hz = bhh[64 + lane], b_hn = bhh[128 + lane];
  for (int q = gw; q < Q; q += nW) {
    const int n0 = q * 4;
    float ir[4] = {0, 0, 0, 0}, iz[4] = {0, 0, 0, 0}, inn[4] = {0, 0, 0, 0};
    float hr[4] = {0, 0, 0, 0}, hz[4] = {0, 0, 0, 0}, hn[4] = {0, 0, 0, 0};
    const float* ap0 = aggH + (size_t)min(n0 + 0, N - 1) * 64;
    const float* ap1 = aggH + (size_t)min(n0 + 1, N - 1) * 64;
    const float* ap2 = aggH + (size_t)min(n0 + 2, N - 1) * 64;
    const float* ap3 = aggH + (size_t)min(n0 + 3, N - 1) * 64;
    const float* hp0 = h + (size_t)min(n0 + 0, N - 1) * 64;
    const float* hp1 = h + (size_t)min(n0 + 1, N - 1) * 64;
    const float* hp2 = h + (size_t)min(n0 + 2, N - 1) * 64;
    const float* hp3 = h + (size_t)min(n0 + 3, N - 1) * 64;
#pragma unroll 4
    for (int k = 0; k < 64; ++k) {
      const float* wrow = Wc + k * WSTRIDE;
      float w0 = wrow[lane], w1 = wrow[64 + lane], w2 = wrow[128 + lane];
      float w3 = wrow[192 + lane], w4 = wrow[256 + lane], w5 = wrow[320 + lane];
      float a0 = ap0[k], a1 = ap1[k], a2 = ap2[k], a3 = ap3[k];
      float g0 = hp0[k], g1 = hp1[k], g2 = hp2[k], g3 = hp3[k];
      ir[0] += w0 * a0; iz[0] += w1 * a0; inn[0] += w2 * a0;
      hr[0] += w3 * g0; hz[0] += w4 * g0; hn[0] += w5 * g0;
      ir[1] += w0 * a1; iz[1] += w1 * a1; inn[1] += w2 * a1;
      hr[1] += w3 * g1; hz[1] += w4 * g1; hn[1] += w5 * g1;
      ir[2] += w0 * a2; iz[2] += w1 * a2; inn[2] += w2 * a2;
      hr[2] += w3 * g2; hz[2] += w4 * g2; hn[2] += w5 * g2;
      ir[3] += w0 * a3; iz[3] += w1 * a3; inn[3] += w2 * a3;
      hr[3] += w3 * g3; hz[3] += w4 * g3; hn[3] += w5 * g3;
    }
#pragma unroll
    for (int qq = 0; qq < 4; ++qq) {
      int n = n0 + qq;
      if (n < N) {
        float hs = h[(size_t)n * 64 + lane];
        float r = sigmoidf_(ir[qq] + b_ir + hr[qq] + b_hr);
        float z = sigmoidf_(iz[qq] + b_iz + hz[qq] + b_hz);
        float nv = tanhf_(inn[qq] + b_in + r * (hn[qq] + b_hn));
        float o = (1.0f - z) * nv + z * hs;
        h[(size_t)n * 64 + lane] = fmaxf(o, 0.0f);
      }
    }
  }
}

// segment-mean pooling over sorted batch ids (per-wave local accumulate, atomic flush)
__global__ __launch_bounds__(256) void k_pool(const float* __restrict__ h,
                                              const int* __restrict__ batch,
                                              float* __restrict__ psum,
                                              float* __restrict__ pcnt, int N) {
  int lane = threadIdx.x & 63;
  int wid = blockIdx.x * 4 + (threadIdx.x >> 6);
  int base = wid * 64;
  if (base >= N) return;
  int endn = min(base + 64, N);
  float acc = 0.0f, ca = 0.0f;
  int curb = batch[base];
  for (int nn = base; nn < endn; ++nn) {
    int b = batch[nn];
    if (b != curb) {
      atomicAdd(&psum[curb * 64 + lane], acc);
      if (lane == 0) atomicAdd(&pcnt[curb], ca);
      acc = 0.0f; ca = 0.0f; curb = b;
    }
    acc += h[(size_t)nn * 64 + lane];
    ca += 1.0f;
  }
  atomicAdd(&psum[curb * 64 + lane], acc);
  if (lane == 0) atomicAdd(&pcnt[curb], ca);
}

// MLP head: 64 -> 32 -> 16 -> 1, one 64-thread block per batch element
__global__ __launch_bounds__(64) void k_head(const float* __restrict__ psum,
                                             const float* __restrict__ pcnt,
                                             const float* __restrict__ fc1W,
                                             const float* __restrict__ fc1b,
                                             const float* __restrict__ fc2W,
                                             const float* __restrict__ fc2b,
                                             const float* __restrict__ fc3W,
                                             const float* __restrict__ fc3b,
                                             float* __restrict__ out) {
  int b = blockIdx.x;
  int j = threadIdx.x;
  float c = fmaxf(pcnt[b], 1.0f);
  float p = psum[b * 64 + j] / c;
  int j1 = j & 31;
  float y1 = fc1b[j1];
#pragma unroll
  for (int k = 0; k < 64; ++k) y1 += fc1W[j1 * 64 + k] * __shfl(p, k, 64);
  y1 = fmaxf(y1, 0.0f);
  int j2 = j & 15;
  float y2 = fc2b[j2];
#pragma unroll
  for (int k = 0; k < 32; ++k) y2 += fc2W[j2 * 32 + k] * __shfl(y1, k, 64);
  y2 = fmaxf(y2, 0.0f);
  float y = 0.0f;
#pragma unroll
  for (int k = 0; k < 16; ++k) y += fc3W[k] * __shfl(y2, k, 64);
  if (j == 0) out[b] = y + fc3b[0];
}

extern "C" void kernel_launch(void* const* d_in, const int* in_sizes, int n_in,
                              void* d_out, int out_size, void* d_ws, size_t ws_size,
                              hipStream_t stream) {
  const int N = in_sizes[0];
  const int E = in_sizes[1] / 2;
  const int B = out_size;

  const int* x = (const int*)d_in[0];
  const int* eidx = (const int*)d_in[1];
  const int* batch = (const int*)d_in[3];
  const float* emb = (const float*)d_in[4];
  const float* ggcW = (const float*)d_in[7];
  const float* wih = (const float*)d_in[8];
  const float* whh = (const float*)d_in[9];
  const float* bih = (const float*)d_in[10];
  const float* bhh = (const float*)d_in[11];
  const float* fc1W = (const float*)d_in[12];
  const float* fc1b = (const float*)d_in[13];
  const float* fc2W = (const float*)d_in[14];
  const float* fc2b = (const float*)d_in[15];
  const float* fc3W = (const float*)d_in[16];
  const float* fc3b = (const float*)d_in[17];
  float* out = (float*)d_out;

  const int* srcp = eidx;
  const int* dstp = eidx + E;

  char* ws = (char*)d_ws;
  size_t off = 0;
  auto alloc = [&](size_t bytes) -> void* {
    void* p = ws + off;
    off = (off + bytes + 255) & ~(size_t)255;
    return p;
  };
  float* h = (float*)alloc((size_t)N * 64 * 4);
  float* aggH = (float*)alloc((size_t)N * 64 * 4);
  int* rowp = (int*)alloc((size_t)(N + 1) * 4);
  int* cur = (int*)alloc((size_t)N * 4);
  int* ssrc = (int*)alloc((size_t)E * 4);
  const int nC = (N + 255) / 256;
  int* part = (int*)alloc((size_t)nC * 4);
  int* coff = (int*)alloc((size_t)nC * 4);
  float* Wp = (float*)alloc((size_t)192 * 64 * 4);
  float* pool = (float*)alloc((size_t)(B * 64 + B) * 4);
  float* psum = pool;
  float* pcnt = pool + (size_t)B * 64;

  // --- build CSR (dst-sorted edge list), once per launch ---
  hipMemsetAsync(cur, 0, (size_t)N * 4, stream);
  k_embed<<<(N * 64 + 255) / 256, 256, 0, stream>>>(x, emb, h, N);
  k_count<<<(E + 255) / 256, 256, 0, stream>>>(dstp, cur, E);
  k_scan1<<<nC, 256, 0, stream>>>(cur, part, N);
  k_scan2<<<1, 512, 0, stream>>>(part, coff, nC);
  k_scan3<<<nC, 256, 0, stream>>>(cur, coff, rowp, N, E);
  hipMemsetAsync(cur, 0, (size_t)N * 4, stream);
  k_fill<<<(E + 255) / 256, 256, 0, stream>>>(srcp, dstp, rowp, cur, ssrc, E);

  // --- 3 GGC+GRU layers (ggc_W folded into GRU input weights) ---
  for (int l = 0; l < 3; ++l) {
    k_wcomb<<<(192 * 64 + 255) / 256, 256, 0, stream>>>(
        wih + (size_t)l * 192 * 64, ggcW + (size_t)l * 64 * 64, Wp);
    k_agg<<<(N + 3) / 4, 256, 0, stream>>>(h, rowp, ssrc, aggH, N);
    k_gru<<<512, 256, 64 * WSTRIDE * 4, stream>>>(
        h, aggH, Wp, whh + (size_t)l * 192 * 64, bih + (size_t)l * 192,
        bhh + (size_t)l * 192, N);
  }

  // --- mean pool + MLP head ---
  hipMemsetAsync(pool, 0, (size_t)(B * 64 + B) * 4, stream);
  int nwaves = (N + 63) / 64;
  k_pool<<<(nwaves + 3) / 4, 256, 0, stream>>>(h, batch, psum, pcnt, N);
  k_head<<<B, 64, 0, stream>>>(psum, pcnt, fc1W, fc1b, fc2W, fc2b, fc3W, fc3b, out);
}

// Round 2
// 616.245 us; speedup vs baseline: 1.7101x; 1.7101x over previous
//
#include <hip/hip_runtime.h>
#include <cstdint>

using s8v = __attribute__((ext_vector_type(8))) short;
using f4v = __attribute__((ext_vector_type(4))) float;

__device__ __forceinline__ float sigmoidf_(float x) {
  return 1.0f / (1.0f + __expf(-x));
}
__device__ __forceinline__ float tanhf_(float x) {
  return 2.0f / (1.0f + __expf(-2.0f * x)) - 1.0f;
}

__device__ __forceinline__ unsigned short bf16_rne(float x) {
  unsigned u = __builtin_bit_cast(unsigned, x);
  unsigned r = (u + 0x7FFF + ((u >> 16) & 1)) >> 16;
  return (unsigned short)r;
}
__device__ __forceinline__ float bf16_to_f32(unsigned short s) {
  unsigned u = ((unsigned)s) << 16;
  return __builtin_bit_cast(float, u);
}

// h[i][j] = emb[x[i]][j]
__global__ __launch_bounds__(256) void k_embed(const int* __restrict__ x,
                                               const float* __restrict__ emb,
                                               float* __restrict__ h, int N) {
  int idx = blockIdx.x * 256 + threadIdx.x;
  if (idx >= N * 64) return;
  int i = idx >> 6, j = idx & 63;
  h[idx] = emb[x[i] * 64 + j];
}

__global__ __launch_bounds__(256) void k_count(const int* __restrict__ dst,
                                               int* __restrict__ cnt, int E) {
  int e = blockIdx.x * 256 + threadIdx.x;
  if (e < E) atomicAdd(&cnt[dst[e]], 1);
}

__global__ __launch_bounds__(256) void k_scan1(const int* __restrict__ cnt,
                                               int* __restrict__ part, int N) {
  __shared__ int s[256];
  int i = blockIdx.x * 256 + threadIdx.x;
  s[threadIdx.x] = (i < N) ? cnt[i] : 0;
  __syncthreads();
  for (int off = 128; off > 0; off >>= 1) {
    if (threadIdx.x < off) s[threadIdx.x] += s[threadIdx.x + off];
    __syncthreads();
  }
  if (threadIdx.x == 0) part[blockIdx.x] = s[0];
}

__global__ __launch_bounds__(512) void k_scan2(const int* __restrict__ part,
                                               int* __restrict__ coff, int nC) {
  __shared__ int s[512];
  int t = threadIdx.x;
  int v = (t < nC) ? part[t] : 0;
  s[t] = v;
  __syncthreads();
  for (int off = 1; off < 512; off <<= 1) {
    int xx = (t >= off) ? s[t - off] : 0;
    __syncthreads();
    s[t] += xx;
    __syncthreads();
  }
  if (t < nC) coff[t] = s[t] - v;  // exclusive prefix
}

__global__ __launch_bounds__(256) void k_scan3(const int* __restrict__ cnt,
                                               const int* __restrict__ coff,
                                               int* __restrict__ rowp, int N, int E) {
  __shared__ int s[256];
  int t = threadIdx.x;
  int i = blockIdx.x * 256 + t;
  int v = (i < N) ? cnt[i] : 0;
  s[t] = v;
  __syncthreads();
  for (int off = 1; off < 256; off <<= 1) {
    int xx = (t >= off) ? s[t - off] : 0;
    __syncthreads();
    s[t] += xx;
    __syncthreads();
  }
  if (i < N) rowp[i] = coff[blockIdx.x] + s[t] - v;
  if (blockIdx.x == 0 && t == 0) rowp[N] = E;
}

__global__ __launch_bounds__(256) void k_fill(const int* __restrict__ src,
                                              const int* __restrict__ dst,
                                              const int* __restrict__ rowp,
                                              int* __restrict__ cur,
                                              int* __restrict__ ssrc, int E) {
  int e = blockIdx.x * 256 + threadIdx.x;
  if (e >= E) return;
  int d = dst[e];
  int pos = rowp[d] + atomicAdd(&cur[d], 1);
  ssrc[pos] = src[e];
}

// Wp[row][t] = sum_k wih[row][k] * ggc[t][k]   (192x64 out, row-major)
__global__ __launch_bounds__(256) void k_wcomb(const float* __restrict__ wih,
                                               const float* __restrict__ ggc,
                                               float* __restrict__ Wp) {
  int o = blockIdx.x * 256 + threadIdx.x;
  if (o >= 192 * 64) return;
  int row = o >> 6, t = o & 63;
  const float* a = wih + row * 64;
  const float* b = ggc + t * 64;
  float s = 0.0f;
#pragma unroll
  for (int k = 0; k < 64; ++k) s += a[k] * b[k];
  Wp[o] = s;
}

// Pack B (128 x 256) into per-lane MFMA fragments, split bf16 hi/lo.
// B cols: [0,64)=r_pre (Wp_r ; whh_r), [64,128)=z_pre, [128,192)=inn (Wp_n ; 0),
//         [192,256)=hn (0 ; whh_n).  Frag layout: idx = ((ct*4+t)*64+lane)*8+i,
// holding B[32t + 8*(lane>>4) + i][16*ct + (lane&15)].
__global__ __launch_bounds__(256) void k_pack(const float* __restrict__ Wp,
                                              const float* __restrict__ whh,
                                              unsigned short* __restrict__ Bhi,
                                              unsigned short* __restrict__ Blo) {
  int tid = blockIdx.x * 256 + threadIdx.x;
  if (tid >= 4096) return;
  int lane = tid & 63;
  int t = (tid >> 6) & 3;
  int ct = tid >> 8;
  int c = ct * 16 + (lane & 15);
  int g = c >> 6, j = c & 63;
  int kbase = t * 32 + (lane >> 4) * 8;
  unsigned short hi[8], lo[8];
#pragma unroll
  for (int i = 0; i < 8; ++i) {
    int k = kbase + i;
    float v;
    if (g == 0)      v = (k < 64) ? Wp[j * 64 + k]          : whh[j * 64 + (k - 64)];
    else if (g == 1) v = (k < 64) ? Wp[(64 + j) * 64 + k]   : whh[(64 + j) * 64 + (k - 64)];
    else if (g == 2) v = (k < 64) ? Wp[(128 + j) * 64 + k]  : 0.0f;
    else             v = (k < 64) ? 0.0f                    : whh[(128 + j) * 64 + (k - 64)];
    hi[i] = bf16_rne(v);
    lo[i] = bf16_rne(v - bf16_to_f32(hi[i]));
  }
#pragma unroll
  for (int i = 0; i < 8; ++i) {
    Bhi[(size_t)tid * 8 + i] = hi[i];
    Blo[(size_t)tid * 8 + i] = lo[i];
  }
}

// aggH[n][j] = sum over incoming edges of h[src][j]  (CSR gather)
__global__ __launch_bounds__(256) void k_agg(const float* __restrict__ h,
                                             const int* __restrict__ rowp,
                                             const int* __restrict__ ssrc,
                                             float* __restrict__ aggH, int N) {
  int lane = threadIdx.x & 63;
  int n = blockIdx.x * 4 + (threadIdx.x >> 6);
  if (n >= N) return;
  int beg = rowp[n], end = rowp[n + 1];
  float acc = 0.0f;
  for (int e = beg; e < end; ++e) {
    int s = ssrc[e];
    acc += h[(size_t)s * 64 + lane];
  }
  aggH[(size_t)n * 64 + lane] = acc;
}

__device__ __forceinline__ void f32x8_to_split(const float* __restrict__ p,
                                               s8v& hi, s8v& lo) {
  f4v x0 = *(const f4v*)p;
  f4v x1 = *(const f4v*)(p + 4);
#pragma unroll
  for (int i = 0; i < 4; ++i) {
    unsigned short hs = bf16_rne(x0[i]);
    hi[i] = (short)hs;
    lo[i] = (short)bf16_rne(x0[i] - bf16_to_f32(hs));
  }
#pragma unroll
  for (int i = 0; i < 4; ++i) {
    unsigned short hs = bf16_rne(x1[i]);
    hi[4 + i] = (short)hs;
    lo[4 + i] = (short)bf16_rne(x1[i] - bf16_to_f32(hs));
  }
}

#define LSTRIDE 260  // 256 cols + 4 pad (2-way max bank aliasing on MFMA store)

// Fused GRU via split-bf16 MFMA: [aggH | h] (N x 128) @ B (128 x 256) -> gates -> h
__global__ __launch_bounds__(256, 2) void k_gru2(float* __restrict__ h,
                                                 const float* __restrict__ aggH,
                                                 const unsigned short* __restrict__ Bhi,
                                                 const unsigned short* __restrict__ Blo,
                                                 const float* __restrict__ bih,
                                                 const float* __restrict__ bhh,
                                                 int N, int nTiles) {
  __shared__ float buf[16 * LSTRIDE];
  const int lane = threadIdx.x & 63;
  const int w = threadIdx.x >> 6;
  const int r15 = lane & 15;
  const int kg = (lane >> 4) * 8;

  // Register-resident B fragments (this wave's 64 output cols = gate group w)
  s8v bh[4][4], bl[4][4];
#pragma unroll
  for (int ct = 0; ct < 4; ++ct) {
#pragma unroll
    for (int t = 0; t < 4; ++t) {
      int ctg = 4 * w + ct;
      size_t idx = ((size_t)(ctg * 4 + t) * 64 + lane) * 8;
      bh[ct][t] = *(const s8v*)(Bhi + idx);
      bl[ct][t] = *(const s8v*)(Blo + idx);
    }
  }

  for (int tile = blockIdx.x; tile < nTiles; tile += gridDim.x) {
    const int n0 = tile * 16;
    const int row = min(n0 + r15, N - 1);
    s8v ah[4], al[4];
#pragma unroll
    for (int t = 0; t < 2; ++t)
      f32x8_to_split(aggH + (size_t)row * 64 + t * 32 + kg, ah[t], al[t]);
#pragma unroll
    for (int t = 0; t < 2; ++t)
      f32x8_to_split(h + (size_t)row * 64 + t * 32 + kg, ah[2 + t], al[2 + t]);

    f4v acc[4];
#pragma unroll
    for (int ct = 0; ct < 4; ++ct) acc[ct] = (f4v){0.0f, 0.0f, 0.0f, 0.0f};
#pragma unroll
    for (int t = 0; t < 4; ++t) {
#pragma unroll
      for (int ct = 0; ct < 4; ++ct) {
        acc[ct] = __builtin_amdgcn_mfma_f32_16x16x32_bf16(ah[t], bh[ct][t], acc[ct], 0, 0, 0);
        acc[ct] = __builtin_amdgcn_mfma_f32_16x16x32_bf16(ah[t], bl[ct][t], acc[ct], 0, 0, 0);
        acc[ct] = __builtin_amdgcn_mfma_f32_16x16x32_bf16(al[t], bh[ct][t], acc[ct], 0, 0, 0);
      }
    }
    // C/D layout: col = lane&15, row = (lane>>4)*4 + q  [verified m89]
    const int rb = (lane >> 4) * 4;
#pragma unroll
    for (int ct = 0; ct < 4; ++ct)
#pragma unroll
      for (int q = 0; q < 4; ++q)
        buf[(rb + q) * LSTRIDE + w * 64 + ct * 16 + r15] = acc[ct][q];
    __syncthreads();

    // epilogue: gates + relu, in-place h update (row-local, safe)
    const int j = lane;
#pragma unroll
    for (int s = 0; s < 4; ++s) {
      int node = w + 4 * s;
      int n = n0 + node;
      if (n < N) {
        float rp = buf[node * LSTRIDE + j];
        float zp = buf[node * LSTRIDE + 64 + j];
        float ip = buf[node * LSTRIDE + 128 + j];
        float hp = buf[node * LSTRIDE + 192 + j];
        float hold = h[(size_t)n * 64 + j];
        float r = sigmoidf_(rp + bih[j] + bhh[j]);
        float z = sigmoidf_(zp + bih[64 + j] + bhh[64 + j]);
        float nv = tanhf_(ip + bih[128 + j] + r * (hp + bhh[128 + j]));
        float o = (1.0f - z) * nv + z * hold;
        h[(size_t)n * 64 + j] = fmaxf(o, 0.0f);
      }
    }
    __syncthreads();
  }
}

// segment-mean pooling over sorted batch ids (per-wave local accumulate, atomic flush)
__global__ __launch_bounds__(256) void k_pool(const float* __restrict__ h,
                                              const int* __restrict__ batch,
                                              float* __restrict__ psum,
                                              float* __restrict__ pcnt, int N) {
  int lane = threadIdx.x & 63;
  int wid = blockIdx.x * 4 + (threadIdx.x >> 6);
  int base = wid * 64;
  if (base >= N) return;
  int endn = min(base + 64, N);
  float acc = 0.0f, ca = 0.0f;
  int curb = batch[base];
  for (int nn = base; nn < endn; ++nn) {
    int b = batch[nn];
    if (b != curb) {
      atomicAdd(&psum[curb * 64 + lane], acc);
      if (lane == 0) atomicAdd(&pcnt[curb], ca);
      acc = 0.0f; ca = 0.0f; curb = b;
    }
    acc += h[(size_t)nn * 64 + lane];
    ca += 1.0f;
  }
  atomicAdd(&psum[curb * 64 + lane], acc);
  if (lane == 0) atomicAdd(&pcnt[curb], ca);
}

// MLP head: 64 -> 32 -> 16 -> 1, one 64-thread block per batch element
__global__ __launch_bounds__(64) void k_head(const float* __restrict__ psum,
                                             const float* __restrict__ pcnt,
                                             const float* __restrict__ fc1W,
                                             const float* __restrict__ fc1b,
                                             const float* __restrict__ fc2W,
                                             const float* __restrict__ fc2b,
                                             const float* __restrict__ fc3W,
                                             const float* __restrict__ fc3b,
                                             float* __restrict__ out) {
  int b = blockIdx.x;
  int j = threadIdx.x;
  float c = fmaxf(pcnt[b], 1.0f);
  float p = psum[b * 64 + j] / c;
  int j1 = j & 31;
  float y1 = fc1b[j1];
#pragma unroll
  for (int k = 0; k < 64; ++k) y1 += fc1W[j1 * 64 + k] * __shfl(p, k, 64);
  y1 = fmaxf(y1, 0.0f);
  int j2 = j & 15;
  float y2 = fc2b[j2];
#pragma unroll
  for (int k = 0; k < 32; ++k) y2 += fc2W[j2 * 32 + k] * __shfl(y1, k, 64);
  y2 = fmaxf(y2, 0.0f);
  float y = 0.0f;
#pragma unroll
  for (int k = 0; k < 16; ++k) y += fc3W[k] * __shfl(y2, k, 64);
  if (j == 0) out[b] = y + fc3b[0];
}

extern "C" void kernel_launch(void* const* d_in, const int* in_sizes, int n_in,
                              void* d_out, int out_size, void* d_ws, size_t ws_size,
                              hipStream_t stream) {
  const int N = in_sizes[0];
  const int E = in_sizes[1] / 2;
  const int B = out_size;

  const int* x = (const int*)d_in[0];
  const int* eidx = (const int*)d_in[1];
  const int* batch = (const int*)d_in[3];
  const float* emb = (const float*)d_in[4];
  const float* ggcW = (const float*)d_in[7];
  const float* wih = (const float*)d_in[8];
  const float* whh = (const float*)d_in[9];
  const float* bih = (const float*)d_in[10];
  const float* bhh = (const float*)d_in[11];
  const float* fc1W = (const float*)d_in[12];
  const float* fc1b = (const float*)d_in[13];
  const float* fc2W = (const float*)d_in[14];
  const float* fc2b = (const float*)d_in[15];
  const float* fc3W = (const float*)d_in[16];
  const float* fc3b = (const float*)d_in[17];
  float* out = (float*)d_out;

  const int* srcp = eidx;
  const int* dstp = eidx + E;

  char* ws = (char*)d_ws;
  size_t off = 0;
  auto alloc = [&](size_t bytes) -> void* {
    void* p = ws + off;
    off = (off + bytes + 255) & ~(size_t)255;
    return p;
  };
  float* h = (float*)alloc((size_t)N * 64 * 4);
  float* aggH = (float*)alloc((size_t)N * 64 * 4);
  int* rowp = (int*)alloc((size_t)(N + 1) * 4);
  int* cur = (int*)alloc((size_t)N * 4);
  int* ssrc = (int*)alloc((size_t)E * 4);
  const int nC = (N + 255) / 256;
  int* part = (int*)alloc((size_t)nC * 4);
  int* coff = (int*)alloc((size_t)nC * 4);
  float* Wp = (float*)alloc((size_t)192 * 64 * 4);
  unsigned short* Bhi = (unsigned short*)alloc((size_t)4096 * 8 * 2);
  unsigned short* Blo = (unsigned short*)alloc((size_t)4096 * 8 * 2);
  float* pool = (float*)alloc((size_t)(B * 64 + B) * 4);
  float* psum = pool;
  float* pcnt = pool + (size_t)B * 64;

  // --- build CSR (dst-sorted edge list), once per launch ---
  hipMemsetAsync(cur, 0, (size_t)N * 4, stream);
  k_embed<<<(N * 64 + 255) / 256, 256, 0, stream>>>(x, emb, h, N);
  k_count<<<(E + 255) / 256, 256, 0, stream>>>(dstp, cur, E);
  k_scan1<<<nC, 256, 0, stream>>>(cur, part, N);
  k_scan2<<<1, 512, 0, stream>>>(part, coff, nC);
  k_scan3<<<nC, 256, 0, stream>>>(cur, coff, rowp, N, E);
  hipMemsetAsync(cur, 0, (size_t)N * 4, stream);
  k_fill<<<(E + 255) / 256, 256, 0, stream>>>(srcp, dstp, rowp, cur, ssrc, E);

  const int nTiles = (N + 15) / 16;
  // --- 3 GGC+GRU layers (ggc_W folded into GRU input weights, MFMA GRU) ---
  for (int l = 0; l < 3; ++l) {
    k_wcomb<<<(192 * 64 + 255) / 256, 256, 0, stream>>>(
        wih + (size_t)l * 192 * 64, ggcW + (size_t)l * 64 * 64, Wp);
    k_pack<<<16, 256, 0, stream>>>(Wp, whh + (size_t)l * 192 * 64, Bhi, Blo);
    k_agg<<<(N + 3) / 4, 256, 0, stream>>>(h, rowp, ssrc, aggH, N);
    k_gru2<<<512, 256, 0, stream>>>(h, aggH, Bhi, Blo,
                                    bih + (size_t)l * 192, bhh + (size_t)l * 192,
                                    N, nTiles);
  }

  // --- mean pool + MLP head ---
  hipMemsetAsync(pool, 0, (size_t)(B * 64 + B) * 4, stream);
  int nwaves = (N + 63) / 64;
  k_pool<<<(nwaves + 3) / 4, 256, 0, stream>>>(h, batch, psum, pcnt, N);
  k_head<<<B, 64, 0, stream>>>(psum, pcnt, fc1W, fc1b, fc2W, fc2b, fc3W, fc3b, out);
}

// Round 3
// 451.734 us; speedup vs baseline: 2.3329x; 1.3642x over previous
//
#include <hip/hip_runtime.h>
#include <cstdint>

using s8v = __attribute__((ext_vector_type(8))) short;
using f4v = __attribute__((ext_vector_type(4))) float;

__device__ __forceinline__ float sigmoidf_(float x) {
  return 1.0f / (1.0f + __expf(-x));
}
__device__ __forceinline__ float tanhf_(float x) {
  return 2.0f / (1.0f + __expf(-2.0f * x)) - 1.0f;
}

__device__ __forceinline__ unsigned short bf16_rne(float x) {
  unsigned u = __builtin_bit_cast(unsigned, x);
  unsigned r = (u + 0x7FFF + ((u >> 16) & 1)) >> 16;
  return (unsigned short)r;
}
__device__ __forceinline__ float bf16_to_f32(unsigned short s) {
  unsigned u = ((unsigned)s) << 16;
  return __builtin_bit_cast(float, u);
}

// h[i][j] = emb[x[i]][j]
__global__ __launch_bounds__(256) void k_embed(const int* __restrict__ x,
                                               const float* __restrict__ emb,
                                               float* __restrict__ h, int N) {
  int idx = blockIdx.x * 256 + threadIdx.x;
  if (idx >= N * 64) return;
  int i = idx >> 6, j = idx & 63;
  h[idx] = emb[x[i] * 64 + j];
}

__global__ __launch_bounds__(256) void k_count(const int* __restrict__ dst,
                                               int* __restrict__ cnt, int E) {
  int e = blockIdx.x * 256 + threadIdx.x;
  if (e < E) atomicAdd(&cnt[dst[e]], 1);
}

__global__ __launch_bounds__(256) void k_scan1(const int* __restrict__ cnt,
                                               int* __restrict__ part, int N) {
  __shared__ int s[256];
  int i = blockIdx.x * 256 + threadIdx.x;
  s[threadIdx.x] = (i < N) ? cnt[i] : 0;
  __syncthreads();
  for (int off = 128; off > 0; off >>= 1) {
    if (threadIdx.x < off) s[threadIdx.x] += s[threadIdx.x + off];
    __syncthreads();
  }
  if (threadIdx.x == 0) part[blockIdx.x] = s[0];
}

__global__ __launch_bounds__(512) void k_scan2(const int* __restrict__ part,
                                               int* __restrict__ coff, int nC) {
  __shared__ int s[512];
  int t = threadIdx.x;
  int v = (t < nC) ? part[t] : 0;
  s[t] = v;
  __syncthreads();
  for (int off = 1; off < 512; off <<= 1) {
    int xx = (t >= off) ? s[t - off] : 0;
    __syncthreads();
    s[t] += xx;
    __syncthreads();
  }
  if (t < nC) coff[t] = s[t] - v;  // exclusive prefix
}

__global__ __launch_bounds__(256) void k_scan3(const int* __restrict__ cnt,
                                               const int* __restrict__ coff,
                                               int* __restrict__ rowp, int N, int E) {
  __shared__ int s[256];
  int t = threadIdx.x;
  int i = blockIdx.x * 256 + t;
  int v = (i < N) ? cnt[i] : 0;
  s[t] = v;
  __syncthreads();
  for (int off = 1; off < 256; off <<= 1) {
    int xx = (t >= off) ? s[t - off] : 0;
    __syncthreads();
    s[t] += xx;
    __syncthreads();
  }
  if (i < N) rowp[i] = coff[blockIdx.x] + s[t] - v;
  if (blockIdx.x == 0 && t == 0) rowp[N] = E;
}

__global__ __launch_bounds__(256) void k_fill(const int* __restrict__ src,
                                              const int* __restrict__ dst,
                                              const int* __restrict__ rowp,
                                              int* __restrict__ cur,
                                              int* __restrict__ ssrc, int E) {
  int e = blockIdx.x * 256 + threadIdx.x;
  if (e >= E) return;
  int d = dst[e];
  int pos = rowp[d] + atomicAdd(&cur[d], 1);
  ssrc[pos] = src[e];
}

// Wp[row][t] = sum_k wih[row][k] * ggc[t][k]   (192x64 out, row-major)
__global__ __launch_bounds__(256) void k_wcomb(const float* __restrict__ wih,
                                               const float* __restrict__ ggc,
                                               float* __restrict__ Wp) {
  int o = blockIdx.x * 256 + threadIdx.x;
  if (o >= 192 * 64) return;
  int row = o >> 6, t = o & 63;
  const float* a = wih + row * 64;
  const float* b = ggc + t * 64;
  float s = 0.0f;
#pragma unroll
  for (int k = 0; k < 64; ++k) s += a[k] * b[k];
  Wp[o] = s;
}

// Pack B (128 x 256) into per-lane MFMA fragments, split bf16 hi/lo.
// B cols: [0,64)=r_pre (Wp_r ; whh_r), [64,128)=z_pre, [128,192)=inn (Wp_n ; 0),
//         [192,256)=hn (0 ; whh_n).  Frag layout: idx = ((ct*4+t)*64+lane)*8+i,
// holding B[32t + 8*(lane>>4) + i][16*ct + (lane&15)].
__global__ __launch_bounds__(256) void k_pack(const float* __restrict__ Wp,
                                              const float* __restrict__ whh,
                                              unsigned short* __restrict__ Bhi,
                                              unsigned short* __restrict__ Blo) {
  int tid = blockIdx.x * 256 + threadIdx.x;
  if (tid >= 4096) return;
  int lane = tid & 63;
  int t = (tid >> 6) & 3;
  int ct = tid >> 8;
  int c = ct * 16 + (lane & 15);
  int g = c >> 6, j = c & 63;
  int kbase = t * 32 + (lane >> 4) * 8;
  unsigned short hi[8], lo[8];
#pragma unroll
  for (int i = 0; i < 8; ++i) {
    int k = kbase + i;
    float v;
    if (g == 0)      v = (k < 64) ? Wp[j * 64 + k]          : whh[j * 64 + (k - 64)];
    else if (g == 1) v = (k < 64) ? Wp[(64 + j) * 64 + k]   : whh[(64 + j) * 64 + (k - 64)];
    else if (g == 2) v = (k < 64) ? Wp[(128 + j) * 64 + k]  : 0.0f;
    else             v = (k < 64) ? 0.0f                    : whh[(128 + j) * 64 + (k - 64)];
    hi[i] = bf16_rne(v);
    lo[i] = bf16_rne(v - bf16_to_f32(hi[i]));
  }
#pragma unroll
  for (int i = 0; i < 8; ++i) {
    Bhi[(size_t)tid * 8 + i] = hi[i];
    Blo[(size_t)tid * 8 + i] = lo[i];
  }
}

__device__ __forceinline__ void f32x8_to_split(const float* __restrict__ p,
                                               s8v& hi, s8v& lo) {
  f4v x0 = *(const f4v*)p;
  f4v x1 = *(const f4v*)(p + 4);
#pragma unroll
  for (int i = 0; i < 4; ++i) {
    unsigned short hs = bf16_rne(x0[i]);
    hi[i] = (short)hs;
    lo[i] = (short)bf16_rne(x0[i] - bf16_to_f32(hs));
  }
#pragma unroll
  for (int i = 0; i < 4; ++i) {
    unsigned short hs = bf16_rne(x1[i]);
    hi[4 + i] = (short)hs;
    lo[4 + i] = (short)bf16_rne(x1[i] - bf16_to_f32(hs));
  }
}

#define ASTRIDE 68   // 64 + 4 pad
#define LSTRIDE 260  // 256 + 4 pad

// Fused CSR-gather + GRU (split-bf16 MFMA). Reads hin, writes hout (ping-pong).
// Per block: 16-node tile. Gather: each wave's four 16-lane groups own one node,
// 4-way unrolled edge walk (up to 16 indep 256B loads in flight per wave).
__global__ __launch_bounds__(256, 2) void k_gfu(const float* __restrict__ hin,
                                                float* __restrict__ hout,
                                                const int* __restrict__ rowp,
                                                const int* __restrict__ ssrc,
                                                const unsigned short* __restrict__ Bhi,
                                                const unsigned short* __restrict__ Blo,
                                                const float* __restrict__ bih,
                                                const float* __restrict__ bhh,
                                                int N, int nTiles) {
  __shared__ float aggLds[16 * ASTRIDE];
  __shared__ float hLds[16 * ASTRIDE];
  __shared__ float buf[16 * LSTRIDE];
  const int lane = threadIdx.x & 63;
  const int w = threadIdx.x >> 6;
  const int r15 = lane & 15;
  const int kg8 = (lane >> 4) * 8;

  // Register-resident B fragments (this wave's 64 output cols = gate group w)
  s8v bh[4][4], bl[4][4];
#pragma unroll
  for (int ct = 0; ct < 4; ++ct) {
#pragma unroll
    for (int t = 0; t < 4; ++t) {
      int ctg = 4 * w + ct;
      size_t idx = ((size_t)(ctg * 4 + t) * 64 + lane) * 8;
      bh[ct][t] = *(const s8v*)(Bhi + idx);
      bl[ct][t] = *(const s8v*)(Blo + idx);
    }
  }

  for (int tile = blockIdx.x; tile < nTiles; tile += gridDim.x) {
    const int n0 = tile * 16;
    // ---- gather + h staging ----
    {
      const int g = lane >> 4;
      const int node = 4 * w + g;
      const int n = n0 + node;
      const int nc = min(n, N - 1);
      f4v hv = *(const f4v*)(hin + (size_t)nc * 64 + 4 * r15);
      f4v a0 = {0, 0, 0, 0}, a1 = {0, 0, 0, 0}, a2 = {0, 0, 0, 0}, a3 = {0, 0, 0, 0};
      if (n < N) {
        int e = rowp[n];
        const int end = rowp[n + 1];
        for (; e + 4 <= end; e += 4) {
          int s0 = ssrc[e], s1 = ssrc[e + 1], s2 = ssrc[e + 2], s3 = ssrc[e + 3];
          a0 += *(const f4v*)(hin + (size_t)s0 * 64 + 4 * r15);
          a1 += *(const f4v*)(hin + (size_t)s1 * 64 + 4 * r15);
          a2 += *(const f4v*)(hin + (size_t)s2 * 64 + 4 * r15);
          a3 += *(const f4v*)(hin + (size_t)s3 * 64 + 4 * r15);
        }
        if (e + 2 <= end) {
          int s0 = ssrc[e], s1 = ssrc[e + 1];
          a0 += *(const f4v*)(hin + (size_t)s0 * 64 + 4 * r15);
          a1 += *(const f4v*)(hin + (size_t)s1 * 64 + 4 * r15);
          e += 2;
        }
        if (e < end) {
          int s0 = ssrc[e];
          a2 += *(const f4v*)(hin + (size_t)s0 * 64 + 4 * r15);
        }
      }
      a0 += a1; a2 += a3; a0 += a2;
      *(f4v*)(aggLds + node * ASTRIDE + 4 * r15) = a0;
      *(f4v*)(hLds + node * ASTRIDE + 4 * r15) = hv;
    }
    __syncthreads();

    // ---- A fragments from LDS (split bf16) ----
    s8v ah[4], al[4];
#pragma unroll
    for (int t = 0; t < 2; ++t)
      f32x8_to_split(aggLds + r15 * ASTRIDE + t * 32 + kg8, ah[t], al[t]);
#pragma unroll
    for (int t = 0; t < 2; ++t)
      f32x8_to_split(hLds + r15 * ASTRIDE + t * 32 + kg8, ah[2 + t], al[2 + t]);

    f4v acc[4];
#pragma unroll
    for (int ct = 0; ct < 4; ++ct) acc[ct] = (f4v){0.0f, 0.0f, 0.0f, 0.0f};
#pragma unroll
    for (int t = 0; t < 4; ++t) {
#pragma unroll
      for (int ct = 0; ct < 4; ++ct) {
        acc[ct] = __builtin_amdgcn_mfma_f32_16x16x32_bf16(ah[t], bh[ct][t], acc[ct], 0, 0, 0);
        acc[ct] = __builtin_amdgcn_mfma_f32_16x16x32_bf16(ah[t], bl[ct][t], acc[ct], 0, 0, 0);
        acc[ct] = __builtin_amdgcn_mfma_f32_16x16x32_bf16(al[t], bh[ct][t], acc[ct], 0, 0, 0);
      }
    }
    // C/D layout: col = lane&15, row = (lane>>4)*4 + q  [verified m89]
    const int rb = (lane >> 4) * 4;
#pragma unroll
    for (int ct = 0; ct < 4; ++ct)
#pragma unroll
      for (int q = 0; q < 4; ++q)
        buf[(rb + q) * LSTRIDE + w * 64 + ct * 16 + r15] = acc[ct][q];
    __syncthreads();

    // ---- epilogue: gates + relu -> hout ----
    const int j = lane;
#pragma unroll
    for (int s = 0; s < 4; ++s) {
      int node = w + 4 * s;
      int n = n0 + node;
      if (n < N) {
        float rp = buf[node * LSTRIDE + j];
        float zp = buf[node * LSTRIDE + 64 + j];
        float ip = buf[node * LSTRIDE + 128 + j];
        float hp = buf[node * LSTRIDE + 192 + j];
        float hold = hLds[node * ASTRIDE + j];
        float r = sigmoidf_(rp + bih[j] + bhh[j]);
        float z = sigmoidf_(zp + bih[64 + j] + bhh[64 + j]);
        float nv = tanhf_(ip + bih[128 + j] + r * (hp + bhh[128 + j]));
        float o = (1.0f - z) * nv + z * hold;
        hout[(size_t)n * 64 + j] = fmaxf(o, 0.0f);
      }
    }
    __syncthreads();
  }
}

// segment-mean pooling over sorted batch ids (per-wave local accumulate, atomic flush)
__global__ __launch_bounds__(256) void k_pool(const float* __restrict__ h,
                                              const int* __restrict__ batch,
                                              float* __restrict__ psum,
                                              float* __restrict__ pcnt, int N) {
  int lane = threadIdx.x & 63;
  int wid = blockIdx.x * 4 + (threadIdx.x >> 6);
  int base = wid * 64;
  if (base >= N) return;
  int endn = min(base + 64, N);
  float acc = 0.0f, ca = 0.0f;
  int curb = batch[base];
  for (int nn = base; nn < endn; ++nn) {
    int b = batch[nn];
    if (b != curb) {
      atomicAdd(&psum[curb * 64 + lane], acc);
      if (lane == 0) atomicAdd(&pcnt[curb], ca);
      acc = 0.0f; ca = 0.0f; curb = b;
    }
    acc += h[(size_t)nn * 64 + lane];
    ca += 1.0f;
  }
  atomicAdd(&psum[curb * 64 + lane], acc);
  if (lane == 0) atomicAdd(&pcnt[curb], ca);
}

// MLP head: 64 -> 32 -> 16 -> 1, one 64-thread block per batch element
__global__ __launch_bounds__(64) void k_head(const float* __restrict__ psum,
                                             const float* __restrict__ pcnt,
                                             const float* __restrict__ fc1W,
                                             const float* __restrict__ fc1b,
                                             const float* __restrict__ fc2W,
                                             const float* __restrict__ fc2b,
                                             const float* __restrict__ fc3W,
                                             const float* __restrict__ fc3b,
                                             float* __restrict__ out) {
  int b = blockIdx.x;
  int j = threadIdx.x;
  float c = fmaxf(pcnt[b], 1.0f);
  float p = psum[b * 64 + j] / c;
  int j1 = j & 31;
  float y1 = fc1b[j1];
#pragma unroll
  for (int k = 0; k < 64; ++k) y1 += fc1W[j1 * 64 + k] * __shfl(p, k, 64);
  y1 = fmaxf(y1, 0.0f);
  int j2 = j & 15;
  float y2 = fc2b[j2];
#pragma unroll
  for (int k = 0; k < 32; ++k) y2 += fc2W[j2 * 32 + k] * __shfl(y1, k, 64);
  y2 = fmaxf(y2, 0.0f);
  float y = 0.0f;
#pragma unroll
  for (int k = 0; k < 16; ++k) y += fc3W[k] * __shfl(y2, k, 64);
  if (j == 0) out[b] = y + fc3b[0];
}

extern "C" void kernel_launch(void* const* d_in, const int* in_sizes, int n_in,
                              void* d_out, int out_size, void* d_ws, size_t ws_size,
                              hipStream_t stream) {
  const int N = in_sizes[0];
  const int E = in_sizes[1] / 2;
  const int B = out_size;

  const int* x = (const int*)d_in[0];
  const int* eidx = (const int*)d_in[1];
  const int* batch = (const int*)d_in[3];
  const float* emb = (const float*)d_in[4];
  const float* ggcW = (const float*)d_in[7];
  const float* wih = (const float*)d_in[8];
  const float* whh = (const float*)d_in[9];
  const float* bih = (const float*)d_in[10];
  const float* bhh = (const float*)d_in[11];
  const float* fc1W = (const float*)d_in[12];
  const float* fc1b = (const float*)d_in[13];
  const float* fc2W = (const float*)d_in[14];
  const float* fc2b = (const float*)d_in[15];
  const float* fc3W = (const float*)d_in[16];
  const float* fc3b = (const float*)d_in[17];
  float* out = (float*)d_out;

  const int* srcp = eidx;
  const int* dstp = eidx + E;

  char* ws = (char*)d_ws;
  size_t off = 0;
  auto alloc = [&](size_t bytes) -> void* {
    void* p = ws + off;
    off = (off + bytes + 255) & ~(size_t)255;
    return p;
  };
  float* h0 = (float*)alloc((size_t)N * 64 * 4);
  float* h1 = (float*)alloc((size_t)N * 64 * 4);
  int* rowp = (int*)alloc((size_t)(N + 1) * 4);
  int* cur = (int*)alloc((size_t)N * 4);
  int* ssrc = (int*)alloc((size_t)E * 4);
  const int nC = (N + 255) / 256;
  int* part = (int*)alloc((size_t)nC * 4);
  int* coff = (int*)alloc((size_t)nC * 4);
  float* Wp = (float*)alloc((size_t)192 * 64 * 4);
  unsigned short* Bhi = (unsigned short*)alloc((size_t)4096 * 8 * 2);
  unsigned short* Blo = (unsigned short*)alloc((size_t)4096 * 8 * 2);
  float* pool = (float*)alloc((size_t)(B * 64 + B) * 4);
  float* psum = pool;
  float* pcnt = pool + (size_t)B * 64;

  // --- build CSR (dst-sorted edge list), once per launch ---
  hipMemsetAsync(cur, 0, (size_t)N * 4, stream);
  k_embed<<<(N * 64 + 255) / 256, 256, 0, stream>>>(x, emb, h0, N);
  k_count<<<(E + 255) / 256, 256, 0, stream>>>(dstp, cur, E);
  k_scan1<<<nC, 256, 0, stream>>>(cur, part, N);
  k_scan2<<<1, 512, 0, stream>>>(part, coff, nC);
  k_scan3<<<nC, 256, 0, stream>>>(cur, coff, rowp, N, E);
  hipMemsetAsync(cur, 0, (size_t)N * 4, stream);
  k_fill<<<(E + 255) / 256, 256, 0, stream>>>(srcp, dstp, rowp, cur, ssrc, E);

  const int nTiles = (N + 15) / 16;
  const int grid = nTiles < 2048 ? nTiles : 2048;
  // --- 3 fused GGC+GRU layers (ggc_W folded into GRU input weights) ---
  float* hb[2] = {h0, h1};
  for (int l = 0; l < 3; ++l) {
    k_wcomb<<<(192 * 64 + 255) / 256, 256, 0, stream>>>(
        wih + (size_t)l * 192 * 64, ggcW + (size_t)l * 64 * 64, Wp);
    k_pack<<<16, 256, 0, stream>>>(Wp, whh + (size_t)l * 192 * 64, Bhi, Blo);
    k_gfu<<<grid, 256, 0, stream>>>(hb[l & 1], hb[1 - (l & 1)], rowp, ssrc,
                                    Bhi, Blo, bih + (size_t)l * 192,
                                    bhh + (size_t)l * 192, N, nTiles);
  }
  float* hfin = hb[1];  // after 3 layers: h0->h1->h0->h1

  // --- mean pool + MLP head ---
  hipMemsetAsync(pool, 0, (size_t)(B * 64 + B) * 4, stream);
  int nwaves = (N + 63) / 64;
  k_pool<<<(nwaves + 3) / 4, 256, 0, stream>>>(hfin, batch, psum, pcnt, N);
  k_head<<<B, 64, 0, stream>>>(psum, pcnt, fc1W, fc1b, fc2W, fc2b, fc3W, fc3b, out);
}